// Round 8
// baseline (228.571 us; speedup 1.0000x reference)
//
#include <hip/hip_runtime.h>
#include <hip/hip_bf16.h>

// MaskedAttentionLayer: B=4, N=4096, D=256, fp32 in/out.
// mask keeps strictly-future (m>n); softmax over QUERY axis (per-column).
// O = E @ (V/colsum), E = exp(S/16); col m=0 fully masked -> V[b,0,:]/4096.

typedef float f32x4 __attribute__((ext_vector_type(4)));
typedef __bf16 bf16x8 __attribute__((ext_vector_type(8)));
typedef __bf16 bf16x4 __attribute__((ext_vector_type(4)));

#define MFMA16(a, b, c) __builtin_amdgcn_mfma_f32_16x16x32_bf16((a), (b), (c), 0, 0, 0)

constexpr int SEQ = 4096;
constexpr int DIM = 256;

// async global->LDS DMA, 16B/lane (dest = wave-uniform base + lane*16)
__device__ __forceinline__ void gl16(const __bf16* g, __bf16* l) {
  __builtin_amdgcn_global_load_lds((const __attribute__((address_space(1))) void*)g,
                                   (__attribute__((address_space(3))) void*)l, 16, 0, 0);
}

// ---------------------------------------------------------------- k_prep
__global__ void k_prep(const float* __restrict__ Wq, const float* __restrict__ Wk,
                       const float* __restrict__ Wv, __bf16* __restrict__ Wb,
                       float* __restrict__ colsum) {
  int i = blockIdx.x * 256 + threadIdx.x;
  if (i < 3 * 65536) {
    const float* src = (i < 65536) ? Wq : (i < 131072 ? Wk : Wv);
    Wb[i] = (__bf16)src[i & 65535];
  }
  if (i < 4 * SEQ) colsum[i] = 0.f;
}

// ---------------------------------------------------------------- k_qkv
// (r6-verified, unchanged)
__global__ __launch_bounds__(256, 2) void k_qkv(const float* __restrict__ x,
                                                const __bf16* __restrict__ Wb,
                                                __bf16* __restrict__ Qb,
                                                __bf16* __restrict__ Kb,
                                                __bf16* __restrict__ Vb) {
  __shared__ __bf16 wsh[64][264];
  const int t = threadIdx.x, lane = t & 63, w = t >> 6;
  const int ln = lane & 15, quad = lane >> 4, q8 = quad * 8;
  const int i0 = blockIdx.x * 64;
  bf16x8 xa[8];
#pragma unroll
  for (int kf = 0; kf < 8; ++kf) {
    const float* src = &x[(size_t)(i0 + w * 16 + ln) * DIM + kf * 32 + q8];
    float4 v0 = *(const float4*)&src[0];
    float4 v1 = *(const float4*)&src[4];
    xa[kf] = bf16x8{(__bf16)v0.x, (__bf16)v0.y, (__bf16)v0.z, (__bf16)v0.w,
                    (__bf16)v1.x, (__bf16)v1.y, (__bf16)v1.z, (__bf16)v1.w};
  }
  for (int zj = 0; zj < 12; ++zj) {
    const int z = zj >> 2, j0 = (zj & 3) * 64;
    const __bf16* W = Wb + z * 65536 + j0 * 256;
    bf16x8 stg[8];
#pragma unroll
    for (int i = 0; i < 8; ++i) stg[i] = *(const bf16x8*)&W[(t + i * 256) * 8];
    __syncthreads();
#pragma unroll
    for (int i = 0; i < 8; ++i)
      *(bf16x8*)&wsh[(t >> 5) + i * 8][(t & 31) * 8] = stg[i];
    __syncthreads();
    f32x4 acc[4] = {};
#pragma unroll
    for (int kf = 0; kf < 8; ++kf) {
      bf16x8 bb[4];
#pragma unroll
      for (int tj = 0; tj < 4; ++tj)
        bb[tj] = *(bf16x8*)&wsh[tj * 16 + ln][kf * 32 + q8];
#pragma unroll
      for (int tj = 0; tj < 4; ++tj) acc[tj] = MFMA16(xa[kf], bb[tj], acc[tj]);
    }
    __bf16* Out = (z == 0) ? Qb : (z == 1 ? Kb : Vb);
#pragma unroll
    for (int tj = 0; tj < 4; ++tj)
#pragma unroll
      for (int r = 0; r < 4; ++r) {
        int row = i0 + w * 16 + quad * 4 + r;
        int col = j0 + tj * 16 + ln;
        Out[(size_t)row * DIM + col] = (__bf16)acc[tj][r];
      }
  }
}

// ---------------------------------------------------------------- k_colsum
// (r7-verified, unchanged)
__global__ __launch_bounds__(256, 2) void k_colsum(const __bf16* __restrict__ Qb,
                                                   const __bf16* __restrict__ Kb,
                                                   float* __restrict__ colsum) {
  __shared__ __bf16 qsh[2 * 64 * 256];  // 64 KB, two 32KB buffers
  const int t = threadIdx.x, lane = t & 63, w = t >> 6;
  const int ln = lane & 15, quad = lane >> 4, q8 = quad * 8;
  const int bid = blockIdx.x;
  const int b = (bid & 7) >> 1;                 // XCD-pair pinned batch
  const int i = ((bid >> 3) << 1) | (bid & 1);  // 0..255
  const int round = i >> 6, k = i & 63;
  const int mt = (round & 1) ? 63 - k : k;      // reversal balances CU pairs
  const int s = round;                          // n-chunk split 0..3
  const int m0 = mt * 64;
  const __bf16* Qp = Qb + (size_t)b * SEQ * DIM;
  const __bf16* Kp = Kb + (size_t)b * SEQ * DIM;
  bf16x8 kb[8];
#pragma unroll
  for (int kf = 0; kf < 8; ++kf)
    kb[kf] = *(const bf16x8*)&Kp[(size_t)(m0 + w * 16 + ln) * DIM + kf * 32 + q8];
  auto stageq = [&](int ncv, int buf) {
    const __bf16* src = Qp + (size_t)ncv * 16384;
#pragma unroll
    for (int i2 = 0; i2 < 8; ++i2) {
      int sl = t + i2 * 256;
      int row = sl >> 5, g = sl & 31;
      gl16(&src[row * 256 + ((g ^ (row & 15)) << 3)], &qsh[buf * 16384 + sl * 8]);
    }
  };
  float csum = 0.f;
  int nc = s, cur = 0;
  if (nc <= mt) stageq(nc, 0);
  for (; nc <= mt; nc += 4, cur ^= 1) {
    __syncthreads();
    if (nc + 4 <= mt) stageq(nc + 4, cur ^ 1);
    f32x4 acc[4] = {};
#pragma unroll
    for (int kf = 0; kf < 8; ++kf) {
#pragma unroll
      for (int tn = 0; tn < 4; ++tn) {
        int row = tn * 16 + ln;
        bf16x8 af = *(const bf16x8*)&qsh[cur * 16384 + row * 256 +
                                         (((kf * 4 + quad) ^ ln) << 3)];
        acc[tn] = MFMA16(af, kb[kf], acc[tn]);
      }
    }
    const int m_g = m0 + w * 16 + ln;
#pragma unroll
    for (int tn = 0; tn < 4; ++tn)
#pragma unroll
      for (int r = 0; r < 4; ++r) {
        int n_g = nc * 64 + tn * 16 + quad * 4 + r;
        if (n_g < m_g) csum += __expf(acc[tn][r] * 0.0625f);
      }
  }
  csum += __shfl_xor(csum, 16);
  csum += __shfl_xor(csum, 32);
  if (quad == 0) atomicAdd(&colsum[b * SEQ + m0 + w * 16 + ln], csum);
}

// ---------------------------------------------------------------- k_vpt
// (r5-verified, unchanged) VpTblk[b][mblk64][d][mloc] = V/colsum.
__global__ void k_vpt(const __bf16* __restrict__ Vb, const float* __restrict__ colsum,
                      __bf16* __restrict__ VpT) {
  __shared__ __bf16 tile[64][72];
  const int t = threadIdx.x;
  const int b = blockIdx.z;
  const int m0 = blockIdx.x * 64, d0 = blockIdx.y * 64;
  {
    int row = t >> 2, part = t & 3;
    float cs = colsum[b * SEQ + m0 + row];
    float inv = (m0 + row == 0) ? (1.0f / 4096.0f) : (1.0f / cs);
#pragma unroll
    for (int i = 0; i < 2; ++i) {
      int c = part * 2 + i;
      bf16x8 v = *(const bf16x8*)&Vb[(size_t)(b * SEQ + m0 + row) * DIM + d0 + c * 8];
      bf16x8 o;
#pragma unroll
      for (int j = 0; j < 8; ++j) o[j] = (__bf16)((float)v[j] * inv);
      *(bf16x8*)&tile[row][c * 8] = o;
    }
  }
  __syncthreads();
  {
    int row = t >> 2, part = t & 3;
#pragma unroll
    for (int i = 0; i < 2; ++i) {
      int c = part * 2 + i;
      bf16x8 o;
#pragma unroll
      for (int j = 0; j < 8; ++j) o[j] = tile[c * 8 + j][row];
      *(bf16x8*)&VpT[(size_t)((b * 64 + blockIdx.x) * 256 + d0 + row) * 64 + c * 8] = o;
    }
  }
}

// ---------------------------------------------------------------- k_oinit
// out[b,n,:] = V[b,0,:]/4096 (the fully-masked m=0 column's uniform term).
// Also repairs the harness's 0xAA poison. 2048 blocks x 256, 8 f32/thread.
__global__ void k_oinit(const __bf16* __restrict__ Vb, float* __restrict__ out) {
  const size_t base = ((size_t)blockIdx.x * 256 + threadIdx.x) * 8;
  const int b = (int)(base >> 20);
  const int d0 = (int)(base & 255);
  bf16x8 v0 = *(const bf16x8*)&Vb[((size_t)b << 20) + d0];
  float4 o0, o1;
  o0.x = (float)v0[0] * (1.0f / 4096.0f);
  o0.y = (float)v0[1] * (1.0f / 4096.0f);
  o0.z = (float)v0[2] * (1.0f / 4096.0f);
  o0.w = (float)v0[3] * (1.0f / 4096.0f);
  o1.x = (float)v0[4] * (1.0f / 4096.0f);
  o1.y = (float)v0[5] * (1.0f / 4096.0f);
  o1.z = (float)v0[6] * (1.0f / 4096.0f);
  o1.w = (float)v0[7] * (1.0f / 4096.0f);
  *(float4*)&out[base] = o0;
  *(float4*)&out[base + 4] = o1;
}

// ---------------------------------------------------------------- k_attn v8
// Flat equal-work jobs: (b, nt, chunk c) where chunk c covers the 8 absolute
// m-steps [8c, 8c+7] clipped to [nt, 63]. 288 jobs/batch, 1152 blocks x 256
// thr (4 waves), enumerated c-DESCENDING so co-resident blocks share the
// same 8 K/V tiles (L2 multicast). Epilogue: fp32 unsafeAtomicAdd into out
// (<=8 contributors/elem, L2-resident). S-phase computes S^T (A=K from LDS,
// B=Q regs) so P stores are 4x b64 per wave instead of 16x b16.
__global__ __launch_bounds__(256, 2) void k_attn(const __bf16* __restrict__ Qb,
                                                 const __bf16* __restrict__ Kb,
                                                 const __bf16* __restrict__ Vt_blk,
                                                 float* __restrict__ out) {
  __shared__ __bf16 ksh[64 * 256];  // 32768 B, XOR-swizzled groups
  __shared__ __bf16 vsm[256 * 64];  // 32768 B, XOR-swizzled groups
  __shared__ __bf16 ps[64 * 72];    //  9216 B (pad 8)
  const int t = threadIdx.x, lane = t & 63, w = t >> 6;
  const int ln = lane & 15, quad = lane >> 4, q8 = quad * 8;
  const int wn = w & 1;   // n-half (32 rows) both phases
  const int wm = w >> 1;  // S: m-half (32 cols); PV: d-half (128 cols)
  const int bid = blockIdx.x;
  const int b = (bid & 7) >> 1;                 // XCD-pair pinned batch
  int rem = ((bid >> 3) << 1) | (bid & 1);      // job 0..287
  int c = 7;
  while (rem >= 8 * c + 8) { rem -= 8 * c + 8; --c; }  // c-major, descending
  const int nt = rem;                                  // 0..8c+7
  const int lo = (nt > 8 * c) ? nt : 8 * c;
  const int hi = 8 * c + 7;
  const int n0 = nt * 64;
  const __bf16* Qp = Qb + (size_t)b * SEQ * DIM;
  const __bf16* Kp = Kb + (size_t)b * SEQ * DIM;
  const __bf16* Vt = Vt_blk + (size_t)b * SEQ * DIM;  // [64][256][64] blocked
  // Q fragments: rows [n0 + wn*32, +32): 64 VGPRs.
  bf16x8 qf[2][8];
#pragma unroll
  for (int tn = 0; tn < 2; ++tn)
#pragma unroll
    for (int kf = 0; kf < 8; ++kf)
      qf[tn][kf] = *(const bf16x8*)&Qp[(size_t)(n0 + wn * 32 + tn * 16 + ln) * DIM + kf * 32 + q8];
  auto stageK = [&](int msv) {
    const __bf16* kp = Kp + (size_t)msv * 16384;
#pragma unroll
    for (int i2 = 0; i2 < 8; ++i2) {
      int sl = t + i2 * 256;
      int row = sl >> 5, g = sl & 31;
      gl16(&kp[row * 256 + ((g ^ (row & 15)) << 3)], &ksh[sl * 8]);
    }
  };
  auto stageV = [&](int msv) {
    const __bf16* vp = Vt + (size_t)msv * 16384;
#pragma unroll
    for (int i2 = 0; i2 < 8; ++i2) {
      int sl = t + i2 * 256;
      int d = sl >> 3, g = sl & 7;
      gl16(&vp[d * 64 + ((g ^ (d & 7)) << 3)], &vsm[sl * 8]);
    }
  };
  f32x4 accO[2][8] = {};  // [tn][td]
  stageK(hi);
  stageV(hi);
  __syncthreads();
  for (int ms = hi; ms >= lo; --ms) {
    const int msn = ms - 1;
    // ---- S^T phase: A = K rows (m) from swizzled ksh, B = Q regs (n)
    f32x4 accST[2][2] = {};  // [tm][tn]; C: col=n=ln, row=m=quad*4+r
#pragma unroll
    for (int kf = 0; kf < 8; ++kf) {
      bf16x8 af[2];
#pragma unroll
      for (int tm = 0; tm < 2; ++tm) {
        int row = wm * 32 + tm * 16 + ln;
        af[tm] = *(const bf16x8*)&ksh[row * 256 + (((kf * 4 + quad) ^ ln) << 3)];
      }
#pragma unroll
      for (int tm = 0; tm < 2; ++tm)
#pragma unroll
        for (int tn = 0; tn < 2; ++tn)
          accST[tm][tn] = MFMA16(af[tm], qf[tn][kf], accST[tm][tn]);
    }
    __syncthreads();  // B0: all ksh reads done
    if (msn >= lo) stageK(msn);  // flies over exp + B1 + PV
    // mask + exp -> ps[n][m], m contiguous in r -> b64 stores
#pragma unroll
    for (int tm = 0; tm < 2; ++tm)
#pragma unroll
      for (int tn = 0; tn < 2; ++tn) {
        int n_g = n0 + wn * 32 + tn * 16 + ln;
        int mbase = ms * 64 + wm * 32 + tm * 16 + quad * 4;
        bf16x4 pk;
#pragma unroll
        for (int r = 0; r < 4; ++r) {
          float e = (n_g < mbase + r) ? __expf(accST[tm][tn][r] * 0.0625f) : 0.f;
          pk[r] = (__bf16)e;
        }
        *(bf16x4*)&ps[(wn * 32 + tn * 16 + ln) * 72 + wm * 32 + tm * 16 + quad * 4] = pk;
      }
    __syncthreads();  // B1: ps visible (also drains stageK)
    // ---- PV: O[n][d] += P[n][m] * VpT[d][m], V from swizzled vsm
#pragma unroll
    for (int kf = 0; kf < 2; ++kf) {
      bf16x8 aa[2];
#pragma unroll
      for (int tn = 0; tn < 2; ++tn)
        aa[tn] = *(const bf16x8*)&ps[(wn * 32 + tn * 16 + ln) * 72 + kf * 32 + q8];
#pragma unroll
      for (int td = 0; td < 8; ++td) {
        int d = wm * 128 + td * 16 + ln;
        bf16x8 bb = *(const bf16x8*)&vsm[d * 64 + (((kf * 4 + quad) ^ (ln & 7)) << 3)];
#pragma unroll
        for (int tn = 0; tn < 2; ++tn) accO[tn][td] = MFMA16(aa[tn], bb, accO[tn][td]);
      }
    }
    __syncthreads();  // B2: vsm/ps reads done
    if (msn >= lo) stageV(msn);
    __syncthreads();  // B3: staged tiles visible (drains gl16s)
  }
  // ---- epilogue: fp32 atomic accumulate into out
  float* Op = out + ((size_t)b << 20);
#pragma unroll
  for (int tn = 0; tn < 2; ++tn)
#pragma unroll
    for (int td = 0; td < 8; ++td) {
      int col = wm * 128 + td * 16 + ln;
#pragma unroll
      for (int r = 0; r < 4; ++r) {
        int row = n0 + wn * 32 + tn * 16 + quad * 4 + r;
        unsafeAtomicAdd(&Op[(size_t)row * DIM + col], accO[tn][td][r]);
      }
    }
}

// ---------------------------------------------------------------- launch
extern "C" void kernel_launch(void* const* d_in, const int* in_sizes, int n_in,
                              void* d_out, int out_size, void* d_ws, size_t ws_size,
                              hipStream_t stream) {
  const float* x = (const float*)d_in[0];
  const float* Wq = (const float*)d_in[1];
  const float* Wk = (const float*)d_in[2];
  const float* Wv = (const float*)d_in[3];
  float* out = (float*)d_out;
  char* ws = (char*)d_ws;
  __bf16* Qb = (__bf16*)(ws);                             // 8 MB
  __bf16* Kb = (__bf16*)(ws + (8u << 20));                // 8 MB
  __bf16* Vb = (__bf16*)(ws + (16u << 20));               // 8 MB
  __bf16* VpT = (__bf16*)(ws + (24u << 20));              // 8 MB (blocked)
  float* colsum = (float*)(ws + (32u << 20));             // 64 KB
  __bf16* Wb = (__bf16*)(ws + (32u << 20) + (1u << 16));  // 384 KB

  k_prep<<<dim3(768), dim3(256), 0, stream>>>(Wq, Wk, Wv, Wb, colsum);
  k_qkv<<<dim3(256), dim3(256), 0, stream>>>(x, Wb, Qb, Kb, Vb);
  k_colsum<<<dim3(1024), dim3(256), 0, stream>>>(Qb, Kb, colsum);
  k_vpt<<<dim3(64, 4, 4), dim3(256), 0, stream>>>(Vb, colsum, VpT);
  k_oinit<<<dim3(2048), dim3(256), 0, stream>>>(Vb, out);
  k_attn<<<dim3(1152), dim3(256), 0, stream>>>(Qb, Kb, VpT, out);
}

// Round 9
// 210.064 us; speedup vs baseline: 1.0881x; 1.0881x over previous
//
#include <hip/hip_runtime.h>
#include <hip/hip_bf16.h>

// MaskedAttentionLayer: B=4, N=4096, D=256, fp32 in/out.
// mask keeps strictly-future (m>n); softmax over QUERY axis (per-column).
// O = E @ (V/colsum), E = exp(S/16); col m=0 fully masked -> V[b,0,:]/4096.

typedef float f32x4 __attribute__((ext_vector_type(4)));
typedef __bf16 bf16x8 __attribute__((ext_vector_type(8)));
typedef __bf16 bf16x4 __attribute__((ext_vector_type(4)));

#define MFMA16(a, b, c) __builtin_amdgcn_mfma_f32_16x16x32_bf16((a), (b), (c), 0, 0, 0)

constexpr int SEQ = 4096;
constexpr int DIM = 256;

// async global->LDS DMA, 16B/lane (dest = wave-uniform base + lane*16)
__device__ __forceinline__ void gl16(const __bf16* g, __bf16* l) {
  __builtin_amdgcn_global_load_lds((const __attribute__((address_space(1))) void*)g,
                                   (__attribute__((address_space(3))) void*)l, 16, 0, 0);
}

// ---------------------------------------------------------------- k_prep
__global__ void k_prep(const float* __restrict__ Wq, const float* __restrict__ Wk,
                       const float* __restrict__ Wv, __bf16* __restrict__ Wb,
                       float* __restrict__ colsum) {
  int i = blockIdx.x * 256 + threadIdx.x;
  if (i < 3 * 65536) {
    const float* src = (i < 65536) ? Wq : (i < 131072 ? Wk : Wv);
    Wb[i] = (__bf16)src[i & 65535];
  }
  if (i < 4 * SEQ) colsum[i] = 0.f;
}

// ---------------------------------------------------------------- k_qkv
// (r6-verified, unchanged)
__global__ __launch_bounds__(256, 2) void k_qkv(const float* __restrict__ x,
                                                const __bf16* __restrict__ Wb,
                                                __bf16* __restrict__ Qb,
                                                __bf16* __restrict__ Kb,
                                                __bf16* __restrict__ Vb) {
  __shared__ __bf16 wsh[64][264];
  const int t = threadIdx.x, lane = t & 63, w = t >> 6;
  const int ln = lane & 15, quad = lane >> 4, q8 = quad * 8;
  const int i0 = blockIdx.x * 64;
  bf16x8 xa[8];
#pragma unroll
  for (int kf = 0; kf < 8; ++kf) {
    const float* src = &x[(size_t)(i0 + w * 16 + ln) * DIM + kf * 32 + q8];
    float4 v0 = *(const float4*)&src[0];
    float4 v1 = *(const float4*)&src[4];
    xa[kf] = bf16x8{(__bf16)v0.x, (__bf16)v0.y, (__bf16)v0.z, (__bf16)v0.w,
                    (__bf16)v1.x, (__bf16)v1.y, (__bf16)v1.z, (__bf16)v1.w};
  }
  for (int zj = 0; zj < 12; ++zj) {
    const int z = zj >> 2, j0 = (zj & 3) * 64;
    const __bf16* W = Wb + z * 65536 + j0 * 256;
    bf16x8 stg[8];
#pragma unroll
    for (int i = 0; i < 8; ++i) stg[i] = *(const bf16x8*)&W[(t + i * 256) * 8];
    __syncthreads();
#pragma unroll
    for (int i = 0; i < 8; ++i)
      *(bf16x8*)&wsh[(t >> 5) + i * 8][(t & 31) * 8] = stg[i];
    __syncthreads();
    f32x4 acc[4] = {};
#pragma unroll
    for (int kf = 0; kf < 8; ++kf) {
      bf16x8 bb[4];
#pragma unroll
      for (int tj = 0; tj < 4; ++tj)
        bb[tj] = *(bf16x8*)&wsh[tj * 16 + ln][kf * 32 + q8];
#pragma unroll
      for (int tj = 0; tj < 4; ++tj) acc[tj] = MFMA16(xa[kf], bb[tj], acc[tj]);
    }
    __bf16* Out = (z == 0) ? Qb : (z == 1 ? Kb : Vb);
#pragma unroll
    for (int tj = 0; tj < 4; ++tj)
#pragma unroll
      for (int r = 0; r < 4; ++r) {
        int row = i0 + w * 16 + quad * 4 + r;
        int col = j0 + tj * 16 + ln;
        Out[(size_t)row * DIM + col] = (__bf16)acc[tj][r];
      }
  }
}

// ---------------------------------------------------------------- k_colsum
// (r7-verified, unchanged)
__global__ __launch_bounds__(256, 2) void k_colsum(const __bf16* __restrict__ Qb,
                                                   const __bf16* __restrict__ Kb,
                                                   float* __restrict__ colsum) {
  __shared__ __bf16 qsh[2 * 64 * 256];  // 64 KB, two 32KB buffers
  const int t = threadIdx.x, lane = t & 63, w = t >> 6;
  const int ln = lane & 15, quad = lane >> 4, q8 = quad * 8;
  const int bid = blockIdx.x;
  const int b = (bid & 7) >> 1;                 // XCD-pair pinned batch
  const int i = ((bid >> 3) << 1) | (bid & 1);  // 0..255
  const int round = i >> 6, k = i & 63;
  const int mt = (round & 1) ? 63 - k : k;      // reversal balances CU pairs
  const int s = round;                          // n-chunk split 0..3
  const int m0 = mt * 64;
  const __bf16* Qp = Qb + (size_t)b * SEQ * DIM;
  const __bf16* Kp = Kb + (size_t)b * SEQ * DIM;
  bf16x8 kb[8];
#pragma unroll
  for (int kf = 0; kf < 8; ++kf)
    kb[kf] = *(const bf16x8*)&Kp[(size_t)(m0 + w * 16 + ln) * DIM + kf * 32 + q8];
  auto stageq = [&](int ncv, int buf) {
    const __bf16* src = Qp + (size_t)ncv * 16384;
#pragma unroll
    for (int i2 = 0; i2 < 8; ++i2) {
      int sl = t + i2 * 256;
      int row = sl >> 5, g = sl & 31;
      gl16(&src[row * 256 + ((g ^ (row & 15)) << 3)], &qsh[buf * 16384 + sl * 8]);
    }
  };
  float csum = 0.f;
  int nc = s, cur = 0;
  if (nc <= mt) stageq(nc, 0);
  for (; nc <= mt; nc += 4, cur ^= 1) {
    __syncthreads();
    if (nc + 4 <= mt) stageq(nc + 4, cur ^ 1);
    f32x4 acc[4] = {};
#pragma unroll
    for (int kf = 0; kf < 8; ++kf) {
#pragma unroll
      for (int tn = 0; tn < 4; ++tn) {
        int row = tn * 16 + ln;
        bf16x8 af = *(const bf16x8*)&qsh[cur * 16384 + row * 256 +
                                         (((kf * 4 + quad) ^ ln) << 3)];
        acc[tn] = MFMA16(af, kb[kf], acc[tn]);
      }
    }
    const int m_g = m0 + w * 16 + ln;
#pragma unroll
    for (int tn = 0; tn < 4; ++tn)
#pragma unroll
      for (int r = 0; r < 4; ++r) {
        int n_g = nc * 64 + tn * 16 + quad * 4 + r;
        if (n_g < m_g) csum += __expf(acc[tn][r] * 0.0625f);
      }
  }
  csum += __shfl_xor(csum, 16);
  csum += __shfl_xor(csum, 32);
  if (quad == 0) atomicAdd(&colsum[b * SEQ + m0 + w * 16 + ln], csum);
}

// ---------------------------------------------------------------- k_vpt
// (r5-verified, unchanged) VpTblk[b][mblk64][d][mloc] = V/colsum.
__global__ void k_vpt(const __bf16* __restrict__ Vb, const float* __restrict__ colsum,
                      __bf16* __restrict__ VpT) {
  __shared__ __bf16 tile[64][72];
  const int t = threadIdx.x;
  const int b = blockIdx.z;
  const int m0 = blockIdx.x * 64, d0 = blockIdx.y * 64;
  {
    int row = t >> 2, part = t & 3;
    float cs = colsum[b * SEQ + m0 + row];
    float inv = (m0 + row == 0) ? (1.0f / 4096.0f) : (1.0f / cs);
#pragma unroll
    for (int i = 0; i < 2; ++i) {
      int c = part * 2 + i;
      bf16x8 v = *(const bf16x8*)&Vb[(size_t)(b * SEQ + m0 + row) * DIM + d0 + c * 8];
      bf16x8 o;
#pragma unroll
      for (int j = 0; j < 8; ++j) o[j] = (__bf16)((float)v[j] * inv);
      *(bf16x8*)&tile[row][c * 8] = o;
    }
  }
  __syncthreads();
  {
    int row = t >> 2, part = t & 3;
#pragma unroll
    for (int i = 0; i < 2; ++i) {
      int c = part * 2 + i;
      bf16x8 o;
#pragma unroll
      for (int j = 0; j < 8; ++j) o[j] = tile[c * 8 + j][row];
      *(bf16x8*)&VpT[(size_t)((b * 64 + blockIdx.x) * 256 + d0 + row) * 64 + c * 8] = o;
    }
  }
}

// ---------------------------------------------------------------- k_attn v9
// Flat 4-chunk decomposition: chunk c covers ms in [16c, 16c+15] clipped to
// [nt, 63]. 160 jobs/batch, 640 blocks x 256 thr, longest-first enumeration.
// No-duplication wave partition (LDS-BW bound fix): S^T phase wave owns a
// 16-m strip (A=K read once), B = Q regs for ALL 64 n (qf[4][8]); PV phase
// wave owns a 64-d strip (B=V read once). bf16 partials per chunk -> opart.
__global__ __launch_bounds__(256, 2) void k_attn(const __bf16* __restrict__ Qb,
                                                 const __bf16* __restrict__ Kb,
                                                 const __bf16* __restrict__ Vt_blk,
                                                 __bf16* __restrict__ opart) {
  __shared__ __bf16 ksh[64 * 256];  // 32768 B, XOR-swizzled groups
  __shared__ __bf16 vsm[256 * 64];  // 32768 B, XOR-swizzled groups
  __shared__ __bf16 ps[64 * 72];    //  9216 B (pad 8)
  const int t = threadIdx.x, lane = t & 63, w = t >> 6;
  const int ln = lane & 15, quad = lane >> 4, q8 = quad * 8;
  const int bid = blockIdx.x;
  const int b = (bid & 7) >> 1;                 // XCD-pair pinned batch
  const int j = ((bid >> 3) << 1) | (bid & 1);  // job 0..159, longest first
  int c, nt;
  if (j < 49) { c = 3; nt = j; }
  else if (j < 82) { c = 2; nt = j - 49; }
  else if (j < 99) { c = 1; nt = j - 82; }
  else if (j < 100) { c = 0; nt = 0; }
  else { int p = j - 100; int st = 15 - (p >> 2); c = p & 3; nt = 16 * c + 16 - st; }
  const int hi = 16 * c + 15;
  const int lo = (nt > 16 * c) ? nt : 16 * c;
  const int n0 = nt * 64;
  const __bf16* Qp = Qb + (size_t)b * SEQ * DIM;
  const __bf16* Kp = Kb + (size_t)b * SEQ * DIM;
  const __bf16* Vt = Vt_blk + (size_t)b * SEQ * DIM;  // [64][256][64] blocked
  // Q fragments for ALL 64 n-rows of the tile: 128 VGPRs.
  bf16x8 qf[4][8];
#pragma unroll
  for (int tn = 0; tn < 4; ++tn)
#pragma unroll
    for (int kf = 0; kf < 8; ++kf)
      qf[tn][kf] = *(const bf16x8*)&Qp[(size_t)(n0 + tn * 16 + ln) * DIM + kf * 32 + q8];
  auto stageK = [&](int msv) {
    const __bf16* kp = Kp + (size_t)msv * 16384;
#pragma unroll
    for (int i2 = 0; i2 < 8; ++i2) {
      int sl = t + i2 * 256;
      int row = sl >> 5, g = sl & 31;
      gl16(&kp[row * 256 + ((g ^ (row & 15)) << 3)], &ksh[sl * 8]);
    }
  };
  auto stageV = [&](int msv) {
    const __bf16* vp = Vt + (size_t)msv * 16384;
#pragma unroll
    for (int i2 = 0; i2 < 8; ++i2) {
      int sl = t + i2 * 256;
      int d = sl >> 3, g = sl & 7;
      gl16(&vp[d * 64 + ((g ^ (d & 7)) << 3)], &vsm[sl * 8]);
    }
  };
  f32x4 accO[4][4] = {};  // [tn][td]
  stageK(hi);
  stageV(hi);
  __syncthreads();
  for (int ms = hi; ms >= lo; --ms) {
    const int msn = ms - 1;
    // ---- S^T phase: wave owns m-strip [w*16, +16); A = K row (1 read/kf)
    f32x4 accST[4] = {};  // [tn]; C: col=n=ln, row=m-local=quad*4+r
#pragma unroll
    for (int kf = 0; kf < 8; ++kf) {
      int row = w * 16 + ln;
      bf16x8 af = *(const bf16x8*)&ksh[row * 256 + (((kf * 4 + quad) ^ ln) << 3)];
#pragma unroll
      for (int tn = 0; tn < 4; ++tn) accST[tn] = MFMA16(af, qf[tn][kf], accST[tn]);
    }
    __syncthreads();  // B0: all ksh reads done
    if (msn >= lo) stageK(msn);  // flies over exp + B1 + PV
    // mask + exp -> ps[n][m], m contiguous in r -> b64 stores
#pragma unroll
    for (int tn = 0; tn < 4; ++tn) {
      int n_g = n0 + tn * 16 + ln;
      int mbase = ms * 64 + w * 16 + quad * 4;
      bf16x4 pk;
#pragma unroll
      for (int r = 0; r < 4; ++r) {
        float e = (n_g < mbase + r) ? __expf(accST[tn][r] * 0.0625f) : 0.f;
        pk[r] = (__bf16)e;
      }
      *(bf16x4*)&ps[(tn * 16 + ln) * 72 + w * 16 + quad * 4] = pk;
    }
    __syncthreads();  // B1: ps visible (also drains stageK)
    // ---- PV: wave owns d-strip [w*64, +64); B = V row (1 read per (kf,td))
#pragma unroll
    for (int kf = 0; kf < 2; ++kf) {
      bf16x8 aa[4];
#pragma unroll
      for (int tn = 0; tn < 4; ++tn)
        aa[tn] = *(const bf16x8*)&ps[(tn * 16 + ln) * 72 + kf * 32 + q8];
#pragma unroll
      for (int td = 0; td < 4; ++td) {
        int d = w * 64 + td * 16 + ln;
        bf16x8 bb = *(const bf16x8*)&vsm[d * 64 + (((kf * 4 + quad) ^ (ln & 7)) << 3)];
#pragma unroll
        for (int tn = 0; tn < 4; ++tn) accO[tn][td] = MFMA16(aa[tn], bb, accO[tn][td]);
      }
    }
    __syncthreads();  // B2: vsm/ps reads done
    if (msn >= lo) stageV(msn);
    __syncthreads();  // B3: staged tiles visible (drains gl16s)
  }
  // ---- epilogue: bf16 partial for chunk c
  __bf16* P = opart + (size_t)c * (4u << 20) + ((size_t)b << 20);
#pragma unroll
  for (int tn = 0; tn < 4; ++tn)
#pragma unroll
    for (int td = 0; td < 4; ++td) {
      int col = w * 64 + td * 16 + ln;
#pragma unroll
      for (int r = 0; r < 4; ++r) {
        int row = n0 + tn * 16 + quad * 4 + r;
        P[(size_t)row * DIM + col] = (__bf16)accO[tn][td][r];
      }
    }
}

// ---------------------------------------------------------------- k_final
// Out = sum_c bf16(Opart[c]) + V[b,0,:]/4096. 2048 blocks x 256.
__global__ void k_final(const __bf16* __restrict__ opart, const __bf16* __restrict__ Vb,
                        float* __restrict__ out) {
  const size_t base = ((size_t)blockIdx.x * 256 + threadIdx.x) * 8;
  const int b = (int)(base >> 20);
  const int d0 = (int)(base & 255);
  float sum[8] = {};
#pragma unroll
  for (int s = 0; s < 4; ++s) {
    bf16x8 v = *(const bf16x8*)&opart[(size_t)s * (4u << 20) + base];
#pragma unroll
    for (int j = 0; j < 8; ++j) sum[j] += (float)v[j];
  }
  bf16x8 v0 = *(const bf16x8*)&Vb[((size_t)b << 20) + d0];
  float4 o0, o1;
  o0.x = sum[0] + (float)v0[0] * (1.0f / 4096.0f);
  o0.y = sum[1] + (float)v0[1] * (1.0f / 4096.0f);
  o0.z = sum[2] + (float)v0[2] * (1.0f / 4096.0f);
  o0.w = sum[3] + (float)v0[3] * (1.0f / 4096.0f);
  o1.x = sum[4] + (float)v0[4] * (1.0f / 4096.0f);
  o1.y = sum[5] + (float)v0[5] * (1.0f / 4096.0f);
  o1.z = sum[6] + (float)v0[6] * (1.0f / 4096.0f);
  o1.w = sum[7] + (float)v0[7] * (1.0f / 4096.0f);
  *(float4*)&out[base] = o0;
  *(float4*)&out[base + 4] = o1;
}

// ---------------------------------------------------------------- launch
extern "C" void kernel_launch(void* const* d_in, const int* in_sizes, int n_in,
                              void* d_out, int out_size, void* d_ws, size_t ws_size,
                              hipStream_t stream) {
  const float* x = (const float*)d_in[0];
  const float* Wq = (const float*)d_in[1];
  const float* Wk = (const float*)d_in[2];
  const float* Wv = (const float*)d_in[3];
  float* out = (float*)d_out;
  char* ws = (char*)d_ws;
  __bf16* Qb = (__bf16*)(ws);                             // 8 MB
  __bf16* Kb = (__bf16*)(ws + (8u << 20));                // 8 MB
  __bf16* Vb = (__bf16*)(ws + (16u << 20));               // 8 MB
  __bf16* VpT = (__bf16*)(ws + (24u << 20));              // 8 MB (blocked)
  float* colsum = (float*)(ws + (32u << 20));             // 64 KB
  __bf16* Wb = (__bf16*)(ws + (32u << 20) + (1u << 16));  // 384 KB
  const size_t base = (32u << 20) + (1u << 16) + (384u << 10);
  __bf16* opart = (__bf16*)(ws + base);                   // 32 MB (4 chunks)
  // ws >= base+32MB proven in-session: r6/r7 ran the 4-split path
  // (WRITE_SIZE == 32 MB exactly) and passed re-validation.

  k_prep<<<dim3(768), dim3(256), 0, stream>>>(Wq, Wk, Wv, Wb, colsum);
  k_qkv<<<dim3(256), dim3(256), 0, stream>>>(x, Wb, Qb, Kb, Vb);
  k_colsum<<<dim3(1024), dim3(256), 0, stream>>>(Qb, Kb, colsum);
  k_vpt<<<dim3(64, 4, 4), dim3(256), 0, stream>>>(Vb, colsum, VpT);
  k_attn<<<dim3(640), dim3(256), 0, stream>>>(Qb, Kb, VpT, opart);
  k_final<<<dim3(2048), dim3(256), 0, stream>>>(opart, Vb, out);
}

// Round 10
// 189.052 us; speedup vs baseline: 1.2090x; 1.1111x over previous
//
#include <hip/hip_runtime.h>
#include <hip/hip_bf16.h>

// MaskedAttentionLayer: B=4, N=4096, D=256, fp32 in/out.
// mask keeps strictly-future (m>n); softmax over QUERY axis (per-column).
// O = E @ (V/colsum), E = exp(S/16); col m=0 fully masked -> V[b,0,:]/4096.
//
// r10 restructure: materialize E (unnormalized exp, bf16, upper-tri tiles
// only) -> k_scores (S^T MFMA + fused colsum, 1 barrier/step, direct
// swizzled E stores) ; k_pv = streaming dbuf GEMM over E tiles (1 barrier/
// step, direct fp32 out). Multi-pass over mt-ranges if ws is small.

typedef float f32x4 __attribute__((ext_vector_type(4)));
typedef __bf16 bf16x8 __attribute__((ext_vector_type(8)));
typedef __bf16 bf16x4 __attribute__((ext_vector_type(4)));

#define MFMA16(a, b, c) __builtin_amdgcn_mfma_f32_16x16x32_bf16((a), (b), (c), 0, 0, 0)

constexpr int SEQ = 4096;
constexpr int DIM = 256;

__host__ __device__ inline int tri(int x) { return (x * (x + 1)) >> 1; }

// async global->LDS DMA, 16B/lane (dest = wave-uniform base + lane*16)
__device__ __forceinline__ void gl16(const __bf16* g, __bf16* l) {
  __builtin_amdgcn_global_load_lds((const __attribute__((address_space(1))) void*)g,
                                   (__attribute__((address_space(3))) void*)l, 16, 0, 0);
}

// ---------------------------------------------------------------- k_prep
__global__ void k_prep(const float* __restrict__ Wq, const float* __restrict__ Wk,
                       const float* __restrict__ Wv, __bf16* __restrict__ Wb,
                       float* __restrict__ colsum) {
  int i = blockIdx.x * 256 + threadIdx.x;
  if (i < 3 * 65536) {
    const float* src = (i < 65536) ? Wq : (i < 131072 ? Wk : Wv);
    Wb[i] = (__bf16)src[i & 65535];
  }
  if (i < 4 * SEQ) colsum[i] = 0.f;
}

// ---------------------------------------------------------------- k_qkv
// (r6-verified, unchanged)
__global__ __launch_bounds__(256, 2) void k_qkv(const float* __restrict__ x,
                                                const __bf16* __restrict__ Wb,
                                                __bf16* __restrict__ Qb,
                                                __bf16* __restrict__ Kb,
                                                __bf16* __restrict__ Vb) {
  __shared__ __bf16 wsh[64][264];
  const int t = threadIdx.x, lane = t & 63, w = t >> 6;
  const int ln = lane & 15, quad = lane >> 4, q8 = quad * 8;
  const int i0 = blockIdx.x * 64;
  bf16x8 xa[8];
#pragma unroll
  for (int kf = 0; kf < 8; ++kf) {
    const float* src = &x[(size_t)(i0 + w * 16 + ln) * DIM + kf * 32 + q8];
    float4 v0 = *(const float4*)&src[0];
    float4 v1 = *(const float4*)&src[4];
    xa[kf] = bf16x8{(__bf16)v0.x, (__bf16)v0.y, (__bf16)v0.z, (__bf16)v0.w,
                    (__bf16)v1.x, (__bf16)v1.y, (__bf16)v1.z, (__bf16)v1.w};
  }
  for (int zj = 0; zj < 12; ++zj) {
    const int z = zj >> 2, j0 = (zj & 3) * 64;
    const __bf16* W = Wb + z * 65536 + j0 * 256;
    bf16x8 stg[8];
#pragma unroll
    for (int i = 0; i < 8; ++i) stg[i] = *(const bf16x8*)&W[(t + i * 256) * 8];
    __syncthreads();
#pragma unroll
    for (int i = 0; i < 8; ++i)
      *(bf16x8*)&wsh[(t >> 5) + i * 8][(t & 31) * 8] = stg[i];
    __syncthreads();
    f32x4 acc[4] = {};
#pragma unroll
    for (int kf = 0; kf < 8; ++kf) {
      bf16x8 bb[4];
#pragma unroll
      for (int tj = 0; tj < 4; ++tj)
        bb[tj] = *(bf16x8*)&wsh[tj * 16 + ln][kf * 32 + q8];
#pragma unroll
      for (int tj = 0; tj < 4; ++tj) acc[tj] = MFMA16(xa[kf], bb[tj], acc[tj]);
    }
    __bf16* Out = (z == 0) ? Qb : (z == 1 ? Kb : Vb);
#pragma unroll
    for (int tj = 0; tj < 4; ++tj)
#pragma unroll
      for (int r = 0; r < 4; ++r) {
        int row = i0 + w * 16 + quad * 4 + r;
        int col = j0 + tj * 16 + ln;
        Out[(size_t)row * DIM + col] = (__bf16)acc[tj][r];
      }
  }
}

// ---------------------------------------------------------------- k_scores
// For mt in [mtLo, mtHi): E-tile(nc, mt)[n][m] = masked exp(q_n.k_m/16),
// stored bank-swizzled (16B part q holds logical part q^(n&7)) in packed
// upper-tri layout: tile off = tri(mt)-triLo + nc. Also colsum via atomics
// (fused). Block = (b, mt, s); wave owns 16-m strip (K A-frags in regs);
// Q chunks dbuf via gl16; ONE barrier/step; direct b64 global E stores.
__global__ __launch_bounds__(256, 2) void k_scores(const __bf16* __restrict__ Qb,
                                                   const __bf16* __restrict__ Kb,
                                                   __bf16* __restrict__ E,
                                                   float* __restrict__ colsum,
                                                   int mtLo, int triLo, int ntiles) {
  __shared__ __bf16 qsh[2 * 64 * 256];  // 64 KB dbuf
  const int t = threadIdx.x, lane = t & 63, w = t >> 6;
  const int ln = lane & 15, quad = lane >> 4, q8 = quad * 8;
  const int bid = blockIdx.x;
  const int b = (bid & 7) >> 1;                    // XCD-pair pinned batch
  const int rest = ((bid >> 3) << 1) | (bid & 1);  // 0..4*nmt-1
  const int mt = mtLo + (rest >> 2);
  const int s = rest & 3;
  if (s > mt) return;
  const int m0 = mt * 64;
  const __bf16* Qp = Qb + (size_t)b * SEQ * DIM;
  const __bf16* Kp = Kb + (size_t)b * SEQ * DIM;
  // K A-frags: wave's 16 m-rows, full K=256. 64 VGPRs.
  bf16x8 kb[8];
#pragma unroll
  for (int kf = 0; kf < 8; ++kf)
    kb[kf] = *(const bf16x8*)&Kp[(size_t)(m0 + w * 16 + ln) * DIM + kf * 32 + q8];
  auto stageq = [&](int ncv, int buf) {
    const __bf16* src = Qp + (size_t)ncv * 16384;
#pragma unroll
    for (int i2 = 0; i2 < 8; ++i2) {
      int sl = t + i2 * 256;
      int row = sl >> 5, g = sl & 31;
      gl16(&src[row * 256 + ((g ^ (row & 15)) << 3)], &qsh[buf * 16384 + sl * 8]);
    }
  };
  float csum4[4] = {0.f, 0.f, 0.f, 0.f};
  const int P16 = w * 2 + (quad >> 1);  // 16B m-part index 0..7
  const int sub = (quad & 1) * 4;       // 8B half within the part
  int nc = s, cur = 0;
  if (nc <= mt) stageq(nc, 0);
  for (; nc <= mt; nc += 4, cur ^= 1) {
    __syncthreads();  // Q[cur] staged (gl16 drained; full-step overlap)
    if (nc + 4 <= mt) stageq(nc + 4, cur ^ 1);
    // S^T: A = K rows (m), B = Q rows (n) from LDS
    f32x4 accST[4] = {};
#pragma unroll
    for (int kf = 0; kf < 8; ++kf) {
#pragma unroll
      for (int tn = 0; tn < 4; ++tn) {
        int row = tn * 16 + ln;
        bf16x8 bq = *(const bf16x8*)&qsh[cur * 16384 + row * 256 +
                                         (((kf * 4 + quad) ^ ln) << 3)];
        accST[tn] = MFMA16(kb[kf], bq, accST[tn]);
      }
    }
    // mask + exp -> direct swizzled global b64 stores; csum accumulate
    __bf16* Et = E + ((size_t)b * ntiles + (tri(mt) - triLo) + nc) * 4096;
#pragma unroll
    for (int tn = 0; tn < 4; ++tn) {
      int nl = tn * 16 + ln;
      int n_g = nc * 64 + nl;
      int mb = m0 + w * 16 + quad * 4;
      bf16x4 pk;
#pragma unroll
      for (int r = 0; r < 4; ++r) {
        float e = (n_g < mb + r) ? __expf(accST[tn][r] * 0.0625f) : 0.f;
        csum4[r] += e;
        pk[r] = (__bf16)e;
      }
      *(bf16x4*)&Et[nl * 64 + ((P16 ^ (nl & 7)) << 3) + sub] = pk;
    }
  }
  // colsum: reduce over n (ln lanes within 16-group), one atomic per m
#pragma unroll
  for (int r = 0; r < 4; ++r) {
    float v = csum4[r];
    v += __shfl_xor(v, 1);
    v += __shfl_xor(v, 2);
    v += __shfl_xor(v, 4);
    v += __shfl_xor(v, 8);
    if (ln == 0) atomicAdd(&colsum[b * SEQ + m0 + w * 16 + quad * 4 + r], v);
  }
}

// ---------------------------------------------------------------- k_vpt
// VpTblk[b][mblk][d][m'] = V[b][mblk*64+m][d]/colsum, stored bank-swizzled:
// 16B part q of row d holds logical part q^(d&7). mblk in [mtLo, ...).
__global__ void k_vpt(const __bf16* __restrict__ Vb, const float* __restrict__ colsum,
                      __bf16* __restrict__ VpT, int mtLo) {
  __shared__ __bf16 tile[64][72];
  const int t = threadIdx.x;
  const int b = blockIdx.z;
  const int mblk = mtLo + blockIdx.x;
  const int m0 = mblk * 64, d0 = blockIdx.y * 64;
  {
    int row = t >> 2, part = t & 3;
    float cs = colsum[b * SEQ + m0 + row];
    float inv = (m0 + row == 0) ? (1.0f / 4096.0f) : (1.0f / cs);
#pragma unroll
    for (int i = 0; i < 2; ++i) {
      int c = part * 2 + i;
      bf16x8 v = *(const bf16x8*)&Vb[(size_t)(b * SEQ + m0 + row) * DIM + d0 + c * 8];
      bf16x8 o;
#pragma unroll
      for (int j = 0; j < 8; ++j) o[j] = (__bf16)((float)v[j] * inv);
      *(bf16x8*)&tile[row][c * 8] = o;
    }
  }
  __syncthreads();
  {
    int row = t >> 2, part = t & 3;  // row = d-local
#pragma unroll
    for (int i = 0; i < 2; ++i) {
      int c = part * 2 + i;  // logical m-part
      bf16x8 o;
#pragma unroll
      for (int j = 0; j < 8; ++j) o[j] = tile[c * 8 + j][row];
      *(bf16x8*)&VpT[(size_t)((b * 64 + mblk) * 256 + d0 + row) * 64 +
                     ((c ^ (row & 7)) << 3)] = o;
    }
  }
}

// ---------------------------------------------------------------- k_pv
// O[n-tile][d-half] (+)= sum_{mt in [max(nt,mtLo), mtHi)} E-tile . VpT-half.
// Streaming dbuf GEMM: stage E 8KB + VpT-half 16KB per step via gl16,
// ONE barrier/step. Blocks (b, nt, dh) with nt reversal across dh for
// balance. init (write + V0 term) iff nt >= mtLo, else read-add.
__global__ __launch_bounds__(256, 2) void k_pv(const __bf16* __restrict__ E,
                                               const __bf16* __restrict__ VpT,
                                               const __bf16* __restrict__ Vb,
                                               float* __restrict__ out,
                                               int mtLo, int mtHi, int triLo,
                                               int ntiles) {
  __shared__ __bf16 esh[2 * 64 * 64];    // 16 KB dbuf
  __shared__ __bf16 vsh[2 * 128 * 64];   // 32 KB dbuf
  const int t = threadIdx.x, lane = t & 63, w = t >> 6;
  const int ln = lane & 15, quad = lane >> 4;
  const int nh = w & 1, dq = w >> 1;  // wave: 32n x 64d quadrant
  const int bid = blockIdx.x;
  const int b = (bid & 7) >> 1;                   // XCD-pair pinned batch
  const int idx = ((bid >> 3) << 1) | (bid & 1);  // 0..2*mtHi-1
  const int nnt = mtHi;
  const int dh = (idx >= nnt) ? 1 : 0;
  const int k = dh ? idx - nnt : idx;
  const int nt = dh ? (nnt - 1 - k) : k;          // reversal balances pairs
  const int mtStart = (nt > mtLo) ? nt : mtLo;
  const int n0 = nt * 64;
  const __bf16* Vt = VpT + (size_t)b * SEQ * DIM;
  auto stageE = [&](int msv, int buf) {
    const __bf16* ep = E + ((size_t)b * ntiles + (tri(msv) - triLo) + nt) * 4096;
#pragma unroll
    for (int i2 = 0; i2 < 2; ++i2) {
      int sl = t + i2 * 256;
      gl16(&ep[sl * 8], &esh[buf * 4096 + sl * 8]);
    }
  };
  auto stageVp = [&](int msv, int buf) {
    const __bf16* vp = Vt + (size_t)msv * 16384 + dh * 8192;
#pragma unroll
    for (int i2 = 0; i2 < 4; ++i2) {
      int sl = t + i2 * 256;
      gl16(&vp[sl * 8], &vsh[buf * 8192 + sl * 8]);
    }
  };
  f32x4 accO[2][4] = {};  // [tn][td]
  int cur = 0;
  stageE(mtHi - 1, 0);
  stageVp(mtHi - 1, 0);
  for (int ms = mtHi - 1; ms >= mtStart; --ms, cur ^= 1) {
    __syncthreads();  // buf[cur] staged (full-step overlap); buf[cur^1] free
    if (ms - 1 >= mtStart) { stageE(ms - 1, cur ^ 1); stageVp(ms - 1, cur ^ 1); }
#pragma unroll
    for (int kf = 0; kf < 2; ++kf) {
      bf16x8 aa[2], bb[4];
#pragma unroll
      for (int tn = 0; tn < 2; ++tn) {
        int row = nh * 32 + tn * 16 + ln;
        aa[tn] = *(const bf16x8*)&esh[cur * 4096 + row * 64 +
                                      (((kf * 4 + quad) ^ (row & 7)) << 3)];
      }
#pragma unroll
      for (int td = 0; td < 4; ++td) {
        int rl = dq * 64 + td * 16 + ln;
        bb[td] = *(const bf16x8*)&vsh[cur * 8192 + rl * 64 +
                                      (((kf * 4 + quad) ^ (rl & 7)) << 3)];
      }
#pragma unroll
      for (int tn = 0; tn < 2; ++tn)
#pragma unroll
        for (int td = 0; td < 4; ++td)
          accO[tn][td] = MFMA16(aa[tn], bb[td], accO[tn][td]);
    }
  }
  // epilogue: direct fp32 out (init with V0 term, or read-add)
  float* Op = out + ((size_t)b << 20);
  const __bf16* V0 = Vb + ((size_t)b << 20);
  const bool init = (nt >= mtLo);
#pragma unroll
  for (int tn = 0; tn < 2; ++tn)
#pragma unroll
    for (int td = 0; td < 4; ++td) {
      int col = dh * 128 + dq * 64 + td * 16 + ln;
      float c0 = init ? (float)V0[col] * (1.0f / 4096.0f) : 0.f;
#pragma unroll
      for (int r = 0; r < 4; ++r) {
        int row = n0 + nh * 32 + tn * 16 + quad * 4 + r;
        float* p = &Op[(size_t)row * DIM + col];
        float v = accO[tn][td][r] + c0;
        if (!init) v += *p;
        *p = v;
      }
    }
}

// ---------------------------------------------------------------- launch
extern "C" void kernel_launch(void* const* d_in, const int* in_sizes, int n_in,
                              void* d_out, int out_size, void* d_ws, size_t ws_size,
                              hipStream_t stream) {
  const float* x = (const float*)d_in[0];
  const float* Wq = (const float*)d_in[1];
  const float* Wk = (const float*)d_in[2];
  const float* Wv = (const float*)d_in[3];
  float* out = (float*)d_out;
  char* ws = (char*)d_ws;
  __bf16* Qb = (__bf16*)(ws);                             // 8 MB
  __bf16* Kb = (__bf16*)(ws + (8u << 20));                // 8 MB
  __bf16* Vb = (__bf16*)(ws + (16u << 20));               // 8 MB
  __bf16* VpT = (__bf16*)(ws + (24u << 20));              // 8 MB (blocked+swizzled)
  float* colsum = (float*)(ws + (32u << 20));             // 64 KB
  __bf16* Wb = (__bf16*)(ws + (32u << 20) + (1u << 16));  // 384 KB
  const size_t base2 = (32u << 20) + (1u << 16) + (384u << 10);
  __bf16* E = (__bf16*)(ws + base2);
  // pass schedule by ws capacity (constant per session -> capture-safe)
  const size_t fullE = (size_t)4 * 2080 * 4096 * sizeof(__bf16);  // 68.2 MB
  int nPass, lo[3], hi[3];
  if (ws_size >= base2 + fullE) {
    nPass = 1; lo[0] = 0; hi[0] = 64;
  } else {  // 3 near-equal-tile passes; E <= 23.9 MB, total < proven 64.4 MB
    nPass = 3;
    lo[0] = 0;  hi[0] = 37;
    lo[1] = 37; hi[1] = 53;
    lo[2] = 53; hi[2] = 64;
  }

  k_prep<<<dim3(768), dim3(256), 0, stream>>>(Wq, Wk, Wv, Wb, colsum);
  k_qkv<<<dim3(256), dim3(256), 0, stream>>>(x, Wb, Qb, Kb, Vb);
  for (int p = 0; p < nPass; ++p) {
    const int nmt = hi[p] - lo[p];
    const int triLo = tri(lo[p]);
    const int ntiles = tri(hi[p]) - triLo;
    k_scores<<<dim3(16 * nmt), dim3(256), 0, stream>>>(Qb, Kb, E, colsum,
                                                       lo[p], triLo, ntiles);
    k_vpt<<<dim3(nmt, 4, 4), dim3(256), 0, stream>>>(Vb, colsum, VpT, lo[p]);
    k_pv<<<dim3(8 * hi[p]), dim3(256), 0, stream>>>(E, VpT, Vb, out,
                                                    lo[p], hi[p], triLo, ntiles);
  }
}

// Round 11
// 179.825 us; speedup vs baseline: 1.2711x; 1.0513x over previous
//
#include <hip/hip_runtime.h>
#include <hip/hip_bf16.h>

// MaskedAttentionLayer: B=4, N=4096, D=256, fp32 in/out.
// mask keeps strictly-future (m>n); softmax over QUERY axis (per-column).
// O = E @ (V/colsum), E = exp(S/16); col m=0 fully masked -> V[b,0,:]/4096.
//
// Structure (r10): materialize E (unnormalized exp, bf16, upper-tri tiles
// only) -> k_scores (S^T MFMA + fused colsum, 1 barrier/step, direct
// swizzled E stores) ; k_pv = streaming dbuf GEMM over E tiles (1 barrier/
// step, direct fp32 out). r11: k_pv at 4 blocks/CU (n-tile 32, 40KB LDS).

typedef float f32x4 __attribute__((ext_vector_type(4)));
typedef __bf16 bf16x8 __attribute__((ext_vector_type(8)));
typedef __bf16 bf16x4 __attribute__((ext_vector_type(4)));

#define MFMA16(a, b, c) __builtin_amdgcn_mfma_f32_16x16x32_bf16((a), (b), (c), 0, 0, 0)

constexpr int SEQ = 4096;
constexpr int DIM = 256;

__host__ __device__ inline int tri(int x) { return (x * (x + 1)) >> 1; }

// async global->LDS DMA, 16B/lane (dest = wave-uniform base + lane*16)
__device__ __forceinline__ void gl16(const __bf16* g, __bf16* l) {
  __builtin_amdgcn_global_load_lds((const __attribute__((address_space(1))) void*)g,
                                   (__attribute__((address_space(3))) void*)l, 16, 0, 0);
}

// ---------------------------------------------------------------- k_prep
__global__ void k_prep(const float* __restrict__ Wq, const float* __restrict__ Wk,
                       const float* __restrict__ Wv, __bf16* __restrict__ Wb,
                       float* __restrict__ colsum) {
  int i = blockIdx.x * 256 + threadIdx.x;
  if (i < 3 * 65536) {
    const float* src = (i < 65536) ? Wq : (i < 131072 ? Wk : Wv);
    Wb[i] = (__bf16)src[i & 65535];
  }
  if (i < 4 * SEQ) colsum[i] = 0.f;
}

// ---------------------------------------------------------------- k_qkv
// (r6-verified, unchanged)
__global__ __launch_bounds__(256, 2) void k_qkv(const float* __restrict__ x,
                                                const __bf16* __restrict__ Wb,
                                                __bf16* __restrict__ Qb,
                                                __bf16* __restrict__ Kb,
                                                __bf16* __restrict__ Vb) {
  __shared__ __bf16 wsh[64][264];
  const int t = threadIdx.x, lane = t & 63, w = t >> 6;
  const int ln = lane & 15, quad = lane >> 4, q8 = quad * 8;
  const int i0 = blockIdx.x * 64;
  bf16x8 xa[8];
#pragma unroll
  for (int kf = 0; kf < 8; ++kf) {
    const float* src = &x[(size_t)(i0 + w * 16 + ln) * DIM + kf * 32 + q8];
    float4 v0 = *(const float4*)&src[0];
    float4 v1 = *(const float4*)&src[4];
    xa[kf] = bf16x8{(__bf16)v0.x, (__bf16)v0.y, (__bf16)v0.z, (__bf16)v0.w,
                    (__bf16)v1.x, (__bf16)v1.y, (__bf16)v1.z, (__bf16)v1.w};
  }
  for (int zj = 0; zj < 12; ++zj) {
    const int z = zj >> 2, j0 = (zj & 3) * 64;
    const __bf16* W = Wb + z * 65536 + j0 * 256;
    bf16x8 stg[8];
#pragma unroll
    for (int i = 0; i < 8; ++i) stg[i] = *(const bf16x8*)&W[(t + i * 256) * 8];
    __syncthreads();
#pragma unroll
    for (int i = 0; i < 8; ++i)
      *(bf16x8*)&wsh[(t >> 5) + i * 8][(t & 31) * 8] = stg[i];
    __syncthreads();
    f32x4 acc[4] = {};
#pragma unroll
    for (int kf = 0; kf < 8; ++kf) {
      bf16x8 bb[4];
#pragma unroll
      for (int tj = 0; tj < 4; ++tj)
        bb[tj] = *(bf16x8*)&wsh[tj * 16 + ln][kf * 32 + q8];
#pragma unroll
      for (int tj = 0; tj < 4; ++tj) acc[tj] = MFMA16(xa[kf], bb[tj], acc[tj]);
    }
    __bf16* Out = (z == 0) ? Qb : (z == 1 ? Kb : Vb);
#pragma unroll
    for (int tj = 0; tj < 4; ++tj)
#pragma unroll
      for (int r = 0; r < 4; ++r) {
        int row = i0 + w * 16 + quad * 4 + r;
        int col = j0 + tj * 16 + ln;
        Out[(size_t)row * DIM + col] = (__bf16)acc[tj][r];
      }
  }
}

// ---------------------------------------------------------------- k_scores
// (r10-verified, unchanged) E-tile(nc, mt)[n][m] = masked exp, swizzled,
// packed upper-tri; colsum fused via atomics; 1 barrier/step.
__global__ __launch_bounds__(256, 2) void k_scores(const __bf16* __restrict__ Qb,
                                                   const __bf16* __restrict__ Kb,
                                                   __bf16* __restrict__ E,
                                                   float* __restrict__ colsum,
                                                   int mtLo, int triLo, int ntiles) {
  __shared__ __bf16 qsh[2 * 64 * 256];  // 64 KB dbuf
  const int t = threadIdx.x, lane = t & 63, w = t >> 6;
  const int ln = lane & 15, quad = lane >> 4, q8 = quad * 8;
  const int bid = blockIdx.x;
  const int b = (bid & 7) >> 1;                    // XCD-pair pinned batch
  const int rest = ((bid >> 3) << 1) | (bid & 1);  // 0..4*nmt-1
  const int mt = mtLo + (rest >> 2);
  const int s = rest & 3;
  if (s > mt) return;
  const int m0 = mt * 64;
  const __bf16* Qp = Qb + (size_t)b * SEQ * DIM;
  const __bf16* Kp = Kb + (size_t)b * SEQ * DIM;
  bf16x8 kb[8];
#pragma unroll
  for (int kf = 0; kf < 8; ++kf)
    kb[kf] = *(const bf16x8*)&Kp[(size_t)(m0 + w * 16 + ln) * DIM + kf * 32 + q8];
  auto stageq = [&](int ncv, int buf) {
    const __bf16* src = Qp + (size_t)ncv * 16384;
#pragma unroll
    for (int i2 = 0; i2 < 8; ++i2) {
      int sl = t + i2 * 256;
      int row = sl >> 5, g = sl & 31;
      gl16(&src[row * 256 + ((g ^ (row & 15)) << 3)], &qsh[buf * 16384 + sl * 8]);
    }
  };
  float csum4[4] = {0.f, 0.f, 0.f, 0.f};
  const int P16 = w * 2 + (quad >> 1);  // 16B m-part index 0..7
  const int sub = (quad & 1) * 4;       // 8B half within the part
  int nc = s, cur = 0;
  if (nc <= mt) stageq(nc, 0);
  for (; nc <= mt; nc += 4, cur ^= 1) {
    __syncthreads();  // Q[cur] staged (full-step overlap)
    if (nc + 4 <= mt) stageq(nc + 4, cur ^ 1);
    f32x4 accST[4] = {};
#pragma unroll
    for (int kf = 0; kf < 8; ++kf) {
#pragma unroll
      for (int tn = 0; tn < 4; ++tn) {
        int row = tn * 16 + ln;
        bf16x8 bq = *(const bf16x8*)&qsh[cur * 16384 + row * 256 +
                                         (((kf * 4 + quad) ^ ln) << 3)];
        accST[tn] = MFMA16(kb[kf], bq, accST[tn]);
      }
    }
    __bf16* Et = E + ((size_t)b * ntiles + (tri(mt) - triLo) + nc) * 4096;
#pragma unroll
    for (int tn = 0; tn < 4; ++tn) {
      int nl = tn * 16 + ln;
      int n_g = nc * 64 + nl;
      int mb = m0 + w * 16 + quad * 4;
      bf16x4 pk;
#pragma unroll
      for (int r = 0; r < 4; ++r) {
        float e = (n_g < mb + r) ? __expf(accST[tn][r] * 0.0625f) : 0.f;
        csum4[r] += e;
        pk[r] = (__bf16)e;
      }
      *(bf16x4*)&Et[nl * 64 + ((P16 ^ (nl & 7)) << 3) + sub] = pk;
    }
  }
#pragma unroll
  for (int r = 0; r < 4; ++r) {
    float v = csum4[r];
    v += __shfl_xor(v, 1);
    v += __shfl_xor(v, 2);
    v += __shfl_xor(v, 4);
    v += __shfl_xor(v, 8);
    if (ln == 0) atomicAdd(&colsum[b * SEQ + m0 + w * 16 + quad * 4 + r], v);
  }
}

// ---------------------------------------------------------------- k_vpt
// (r10-verified, unchanged) swizzled VpTblk[b][mblk][d][m'] = V/colsum.
__global__ void k_vpt(const __bf16* __restrict__ Vb, const float* __restrict__ colsum,
                      __bf16* __restrict__ VpT, int mtLo) {
  __shared__ __bf16 tile[64][72];
  const int t = threadIdx.x;
  const int b = blockIdx.z;
  const int mblk = mtLo + blockIdx.x;
  const int m0 = mblk * 64, d0 = blockIdx.y * 64;
  {
    int row = t >> 2, part = t & 3;
    float cs = colsum[b * SEQ + m0 + row];
    float inv = (m0 + row == 0) ? (1.0f / 4096.0f) : (1.0f / cs);
#pragma unroll
    for (int i = 0; i < 2; ++i) {
      int c = part * 2 + i;
      bf16x8 v = *(const bf16x8*)&Vb[(size_t)(b * SEQ + m0 + row) * DIM + d0 + c * 8];
      bf16x8 o;
#pragma unroll
      for (int j = 0; j < 8; ++j) o[j] = (__bf16)((float)v[j] * inv);
      *(bf16x8*)&tile[row][c * 8] = o;
    }
  }
  __syncthreads();
  {
    int row = t >> 2, part = t & 3;  // row = d-local
#pragma unroll
    for (int i = 0; i < 2; ++i) {
      int c = part * 2 + i;  // logical m-part
      bf16x8 o;
#pragma unroll
      for (int j = 0; j < 8; ++j) o[j] = tile[c * 8 + j][row];
      *(bf16x8*)&VpT[(size_t)((b * 64 + mblk) * 256 + d0 + row) * 64 +
                     ((c ^ (row & 7)) << 3)] = o;
    }
  }
}

// ---------------------------------------------------------------- k_pv v2
// O[32n-tile][128d-half] (+)= sum_mt E-half-tile . VpT-half. 4 blocks/CU:
// LDS 40960 B (E 4KB + VpT 16KB, dbuf), 1 barrier/step. Mapping: idx pair
// (2p,2p+1) = same nt32, dh 0/1 (second E read L2-hot, equal work);
// consecutive p interleave long/short nt (quad-balanced CUs).
__global__ __launch_bounds__(256, 4) void k_pv(const __bf16* __restrict__ E,
                                               const __bf16* __restrict__ VpT,
                                               const __bf16* __restrict__ Vb,
                                               float* __restrict__ out,
                                               int mtLo, int mtHi, int triLo,
                                               int ntiles) {
  __shared__ __bf16 esh[2 * 32 * 64];   //  8192 B dbuf
  __shared__ __bf16 vsh[2 * 128 * 64];  // 32768 B dbuf (total 40960)
  const int t = threadIdx.x, lane = t & 63, w = t >> 6;
  const int ln = lane & 15, quad = lane >> 4;
  const int bid = blockIdx.x;
  const int b = (bid & 7) >> 1;                   // XCD-pair pinned batch
  const int idx = ((bid >> 3) << 1) | (bid & 1);  // 0..4*mtHi-1
  const int p = idx >> 1, dh = idx & 1;
  const int nt32 = (p & 1) ? (2 * mtHi - 1 - (p >> 1)) : (p >> 1);
  const int nc = nt32 >> 1, half = nt32 & 1;      // 64-row E tile + half
  const int mtStart = (nc > mtLo) ? nc : mtLo;
  const int n0 = nt32 * 32;
  const __bf16* Vt = VpT + (size_t)b * SEQ * DIM;
  auto stageE = [&](int msv, int buf) {
    const __bf16* ep =
        E + ((size_t)b * ntiles + (tri(msv) - triLo) + nc) * 4096 + half * 2048;
    gl16(&ep[t * 8], &esh[buf * 2048 + t * 8]);
  };
  auto stageVp = [&](int msv, int buf) {
    const __bf16* vp = Vt + (size_t)msv * 16384 + dh * 8192;
#pragma unroll
    for (int i2 = 0; i2 < 4; ++i2) {
      int sl = t + i2 * 256;
      gl16(&vp[sl * 8], &vsh[buf * 8192 + sl * 8]);
    }
  };
  f32x4 accO[2][2] = {};  // [tn][td]
  int cur = 0;
  stageE(mtHi - 1, 0);
  stageVp(mtHi - 1, 0);
  for (int ms = mtHi - 1; ms >= mtStart; --ms, cur ^= 1) {
    __syncthreads();  // buf[cur] staged (full-step overlap); buf[cur^1] free
    if (ms - 1 >= mtStart) { stageE(ms - 1, cur ^ 1); stageVp(ms - 1, cur ^ 1); }
#pragma unroll
    for (int kf = 0; kf < 2; ++kf) {
      bf16x8 aa[2], bb[2];
#pragma unroll
      for (int tn = 0; tn < 2; ++tn) {
        int row = tn * 16 + ln;  // n within the 32-row half (nl&7 == row&7)
        aa[tn] = *(const bf16x8*)&esh[cur * 2048 + row * 64 +
                                      (((kf * 4 + quad) ^ (row & 7)) << 3)];
      }
#pragma unroll
      for (int td = 0; td < 2; ++td) {
        int rl = w * 32 + td * 16 + ln;  // d within the 128-d half
        bb[td] = *(const bf16x8*)&vsh[cur * 8192 + rl * 64 +
                                      (((kf * 4 + quad) ^ (rl & 7)) << 3)];
      }
#pragma unroll
      for (int tn = 0; tn < 2; ++tn)
#pragma unroll
        for (int td = 0; td < 2; ++td)
          accO[tn][td] = MFMA16(aa[tn], bb[td], accO[tn][td]);
    }
  }
  // epilogue: direct fp32 out (init with V0 term, or read-add in later pass)
  float* Op = out + ((size_t)b << 20);
  const __bf16* V0 = Vb + ((size_t)b << 20);
  const bool init = (nc >= mtLo);
#pragma unroll
  for (int tn = 0; tn < 2; ++tn)
#pragma unroll
    for (int td = 0; td < 2; ++td) {
      int col = dh * 128 + w * 32 + td * 16 + ln;
      float c0 = init ? (float)V0[col] * (1.0f / 4096.0f) : 0.f;
#pragma unroll
      for (int r = 0; r < 4; ++r) {
        int row = n0 + tn * 16 + quad * 4 + r;
        float* pp = &Op[(size_t)row * DIM + col];
        float v = accO[tn][td][r] + c0;
        if (!init) v += *pp;
        *pp = v;
      }
    }
}

// ---------------------------------------------------------------- launch
extern "C" void kernel_launch(void* const* d_in, const int* in_sizes, int n_in,
                              void* d_out, int out_size, void* d_ws, size_t ws_size,
                              hipStream_t stream) {
  const float* x = (const float*)d_in[0];
  const float* Wq = (const float*)d_in[1];
  const float* Wk = (const float*)d_in[2];
  const float* Wv = (const float*)d_in[3];
  float* out = (float*)d_out;
  char* ws = (char*)d_ws;
  __bf16* Qb = (__bf16*)(ws);                             // 8 MB
  __bf16* Kb = (__bf16*)(ws + (8u << 20));                // 8 MB
  __bf16* Vb = (__bf16*)(ws + (16u << 20));               // 8 MB
  __bf16* VpT = (__bf16*)(ws + (24u << 20));              // 8 MB (blocked+swizzled)
  float* colsum = (float*)(ws + (32u << 20));             // 64 KB
  __bf16* Wb = (__bf16*)(ws + (32u << 20) + (1u << 16));  // 384 KB
  const size_t base2 = (32u << 20) + (1u << 16) + (384u << 10);
  __bf16* E = (__bf16*)(ws + base2);
  // pass schedule by ws capacity (constant per session -> capture-safe)
  const size_t fullE = (size_t)4 * 2080 * 4096 * sizeof(__bf16);  // 68.2 MB
  int nPass, lo[3], hi[3];
  if (ws_size >= base2 + fullE) {
    nPass = 1; lo[0] = 0; hi[0] = 64;
  } else {  // 3 near-equal-tile passes
    nPass = 3;
    lo[0] = 0;  hi[0] = 37;
    lo[1] = 37; hi[1] = 53;
    lo[2] = 53; hi[2] = 64;
  }

  k_prep<<<dim3(768), dim3(256), 0, stream>>>(Wq, Wk, Wv, Wb, colsum);
  k_qkv<<<dim3(256), dim3(256), 0, stream>>>(x, Wb, Qb, Kb, Vb);
  for (int p = 0; p < nPass; ++p) {
    const int nmt = hi[p] - lo[p];
    const int triLo = tri(lo[p]);
    const int ntiles = tri(hi[p]) - triLo;
    k_scores<<<dim3(16 * nmt), dim3(256), 0, stream>>>(Qb, Kb, E, colsum,
                                                       lo[p], triLo, ntiles);
    k_vpt<<<dim3(nmt, 4, 4), dim3(256), 0, stream>>>(Vb, colsum, VpT, lo[p]);
    k_pv<<<dim3(16 * hi[p]), dim3(256), 0, stream>>>(E, VpT, Vb, out,
                                                     lo[p], hi[p], triLo, ntiles);
  }
}